// Round 10
// baseline (77122.260 us; speedup 1.0000x reference)
//
#include <hip/hip_runtime.h>
#include <math.h>
#include <float.h>

#define B_   256
#define KK_  196    // 14x14
#define GS_  14
#define IN_  768
#define NH_  8
#define QS_  32
#define HD_  96
#define HQ_  256    // NH_*QS_

// ---------------- PE: correctly-rounded f32 of the f32-argument chain ----------------
// div = f32(exp64(arg32)); ang = f32(k)*div; sin/cos in f64 then rounded to f32.
// (numpy's SIMD sin/cos/exp are within ~1-2.5 ulp of these CR values; a 1-2 ulp
// PE diff shifts pooled scores by only ~5e-7 — below flip scale if downstream
// f32 bits match.)
__global__ void k_pe(float* pe32) {
    int e = blockIdx.x * 256 + threadIdx.x;
    if (e >= KK_ * IN_) return;
    int k = e / IN_, i = e - k * IN_;
    int j = i >> 1;
    const float c32 = (float)(-9.210340371976184 / 768.0);  // f32(-ln(1e4)/768)
    float arg = (float)(2 * j) * c32;                        // f32 mul
    float div = (float)exp((double)arg);                     // CR f32 exp
    float ang = (float)k * div;                              // f32 mul
    double vd = (i & 1) ? cos((double)ang) : sin((double)ang);
    pe32[e] = (float)vd;                                     // CR f32 sin/cos
}

// ====== numpy einsum sum_of_products_contig_outstride0_two, SSE3 baseline ======
// Per 16-elem block (vstep=4): ab3=a3*b3+acc; ab2=a2*b2+ab3; ab1=a1*b1+ab2;
// acc=a0*b0+ab1  (mul/add UNFUSED — einsum_sumprod compiled baseline-only).
// Final reduce: (acc0+acc1)+(acc2+acc3) [hadd x2].
__device__ __forceinline__ float np_chain_dot(const float* __restrict__ a,
                                              const float* __restrict__ b, int nblk) {
#pragma clang fp contract(off)
    float ac0 = 0.f, ac1 = 0.f, ac2 = 0.f, ac3 = 0.f;
    for (int blk = 0; blk < nblk; ++blk) {
        const float* xa = a + blk * 16;
        const float* wa = b + blk * 16;
        {
            float t3 = xa[12] * wa[12] + ac0;
            float t2 = xa[8]  * wa[8]  + t3;
            float t1 = xa[4]  * wa[4]  + t2;
            ac0 = xa[0] * wa[0] + t1;
        }
        {
            float t3 = xa[13] * wa[13] + ac1;
            float t2 = xa[9]  * wa[9]  + t3;
            float t1 = xa[5]  * wa[5]  + t2;
            ac1 = xa[1] * wa[1] + t1;
        }
        {
            float t3 = xa[14] * wa[14] + ac2;
            float t2 = xa[10] * wa[10] + t3;
            float t1 = xa[6]  * wa[6]  + t2;
            ac2 = xa[2] * wa[2] + t1;
        }
        {
            float t3 = xa[15] * wa[15] + ac3;
            float t2 = xa[11] * wa[11] + t3;
            float t1 = xa[7]  * wa[7]  + t2;
            ac3 = xa[3] * wa[3] + t1;
        }
    }
    return (ac0 + ac1) + (ac2 + ac3);
}

// qp32[qq][o] = np-bit q = einsum('bqi,oi->bqo', query, W_q)
__global__ void k_qproj_np(const float* __restrict__ query, const float* __restrict__ Wq,
                           float* qp32) {
    int idx = blockIdx.x * 256 + threadIdx.x;
    if (idx >= QS_ * IN_) return;
    int qq = idx / IN_, o = idx - qq * IN_;
    qp32[idx] = np_chain_dot(query + (size_t)qq * IN_, Wq + (size_t)o * IN_, 48);
}

// ====== fused np-f32 score pipeline: k-proj -> attn -> pool -> argmax ======
// block = (b, h). All arithmetic replicates the numpy f32 reference bits.
__global__ __launch_bounds__(256) void k_score_np(const float* __restrict__ origx,
                                                  const float* __restrict__ pe32,
                                                  const float* __restrict__ Wk,
                                                  const float* __restrict__ qp32,
                                                  float* __restrict__ pool,
                                                  int* __restrict__ idxb) {
#pragma clang fp contract(off)
    int b = blockIdx.x >> 3;     // 256 b x 8 h
    int h = blockIdx.x & 7;
    __shared__ float attn_s[QS_][KK_ + 4];   // 32 x 200 (25.6 KB)
    __shared__ float buf[8576];              // staging / ks / pooled (34.3 KB)
    float* bx = buf;                         // x tile   [32][64]
    float* bw = buf + 2048;                  // Wk tile  [96][68]
    int t = threadIdx.x;

    for (int k0 = 0; k0 < KK_; k0 += 32) {
        int rows = (KK_ - k0 < 32) ? (KK_ - k0) : 32;
        int ndots = rows * HD_;
        float acc[12][4];
        #pragma unroll
        for (int s = 0; s < 12; ++s)
            acc[s][0] = acc[s][1] = acc[s][2] = acc[s][3] = 0.f;

        for (int i0 = 0; i0 < IN_; i0 += 64) {
            __syncthreads();
            for (int e = t; e < rows * 64; e += 256) {
                int rr = e >> 6, cc = e & 63;
                int kk = k0 + rr;
                bx[rr * 64 + cc] = origx[((size_t)b * KK_ + kk) * IN_ + i0 + cc]
                                 + pe32[kk * IN_ + i0 + cc];   // f32 x materialization
            }
            for (int e = t; e < HD_ * 64; e += 256) {
                int rr = e >> 6, cc = e & 63;
                bw[rr * 68 + cc] = Wk[((size_t)(h * HD_ + rr)) * IN_ + i0 + cc];
            }
            __syncthreads();
            #pragma unroll
            for (int s = 0; s < 12; ++s) {
                int id = t + 256 * s;
                if (id >= ndots) break;
                int rr = id / HD_, oo = id - rr * HD_;
                const float4* x4 = (const float4*)(bx + rr * 64);
                const float4* w4 = (const float4*)(bw + oo * 68);
                #pragma unroll
                for (int blk = 0; blk < 4; ++blk) {
                    float4 x0 = x4[blk * 4 + 0], x1 = x4[blk * 4 + 1];
                    float4 x2 = x4[blk * 4 + 2], x3 = x4[blk * 4 + 3];
                    float4 w0 = w4[blk * 4 + 0], w1 = w4[blk * 4 + 1];
                    float4 w2 = w4[blk * 4 + 2], w3 = w4[blk * 4 + 3];
                    float t3, t2, t1;
                    t3 = x3.x * w3.x + acc[s][0]; t2 = x2.x * w2.x + t3;
                    t1 = x1.x * w1.x + t2;        acc[s][0] = x0.x * w0.x + t1;
                    t3 = x3.y * w3.y + acc[s][1]; t2 = x2.y * w2.y + t3;
                    t1 = x1.y * w1.y + t2;        acc[s][1] = x0.y * w0.y + t1;
                    t3 = x3.z * w3.z + acc[s][2]; t2 = x2.z * w2.z + t3;
                    t1 = x1.z * w1.z + t2;        acc[s][2] = x0.z * w0.z + t1;
                    t3 = x3.w * w3.w + acc[s][3]; t2 = x2.w * w2.w + t3;
                    t1 = x1.w * w1.w + t2;        acc[s][3] = x0.w * w0.w + t1;
                }
            }
        }
        __syncthreads();
        // ks[kk][oo] = np hadd reduce (reuse buf, stride 100)
        #pragma unroll
        for (int s = 0; s < 12; ++s) {
            int id = t + 256 * s;
            if (id >= ndots) break;
            int rr = id / HD_, oo = id - rr * HD_;
            buf[rr * 100 + oo] = (acc[s][0] + acc[s][1]) + (acc[s][2] + acc[s][3]);
        }
        __syncthreads();
        // attn = einsum('hqd,bhkd->bhqk') np bits: 96-chain (6 blocks)
        int adots = QS_ * rows;
        for (int e = t; e < adots; e += 256) {
            int q = e / rows, kk = e - q * rows;
            attn_s[q][k0 + kk] = np_chain_dot(qp32 + (size_t)q * IN_ + h * HD_,
                                              buf + kk * 100, 6);
        }
        __syncthreads();
    }

    __syncthreads();
    // 3x3 avgpool: sequential row-major in-bounds adds from 0 (pad zeros are
    // exact no-ops), then /9.0f — np shifted-slice transliteration bits.
    for (int e = t; e < QS_ * KK_; e += 256) {
        int q = e / KK_, kk = e - q * KK_;
        int r = kk / GS_, c = kk - r * GS_;
        float s = 0.f;
        for (int di = -1; di <= 1; ++di) {
            int rr = r + di; if (rr < 0 || rr >= GS_) continue;
            for (int dj = -1; dj <= 1; ++dj) {
                int cc = c + dj; if (cc < 0 || cc >= GS_) continue;
                s += attn_s[q][rr * GS_ + cc];
            }
        }
        buf[q * 200 + kk] = s / 9.0f;
    }
    __syncthreads();
    // first-max argmax per q row (np.argmax semantics)
    if (t < QS_) {
        const float* pr = buf + t * 200;
        float m = pr[0]; int im = 0;
        for (int kk = 1; kk < KK_; ++kk) {
            float v = pr[kk];
            if (v > m) { m = v; im = kk; }
        }
        int row = b * HQ_ + h * QS_ + t;
        pool[row] = m;
        idxb[row] = im;
    }
}

// ---------------- value gather GEMM (f32; bf16-level tolerance) ----------------
__global__ __launch_bounds__(256) void k_value(const float* __restrict__ origx,
                                               const float* __restrict__ pe32,
                                               const float* __restrict__ Wv,
                                               const float* __restrict__ pool,
                                               const int* __restrict__ idxb,
                                               float* __restrict__ out) {
    int h = blockIdx.x >> 7;
    int blk = blockIdx.x & 127;
    int t0 = blk * 64;
    __shared__ float xs[64][68];
    __shared__ float wsm[HD_][68];
    __shared__ int   kidx[64];
    __shared__ float pw[64];
    int t = threadIdx.x;
    if (t < 64) {
        int tau = t0 + t;
        int b = tau >> 5, q = tau & 31;
        int row = b * HQ_ + h * QS_ + q;
        kidx[t] = idxb[row];
        pw[t] = pool[row];
    }
    __syncthreads();

    int tg = t & 15;
    int dg = t >> 4;
    float acc[4][6] = {};

    for (int i0 = 0; i0 < IN_; i0 += 64) {
        __syncthreads();
        for (int e = t; e < 64 * 64; e += 256) {
            int rr = e >> 6, cc = e & 63;
            int tau = t0 + rr;
            int b = tau >> 5;
            int kk = kidx[rr];
            xs[rr][cc] = origx[((size_t)b * KK_ + kk) * IN_ + i0 + cc]
                       + pe32[kk * IN_ + i0 + cc];
        }
        for (int e = t; e < HD_ * 64; e += 256) {
            int rr = e >> 6, cc = e & 63;
            wsm[rr][cc] = Wv[((size_t)(h * HD_ + rr)) * IN_ + i0 + cc];
        }
        __syncthreads();
        for (int ii = 0; ii < 64; ii += 4) {
            float4 xv[4], wv[6];
            #pragma unroll
            for (int s = 0; s < 4; ++s) xv[s] = *(const float4*)&xs[4 * tg + s][ii];
            #pragma unroll
            for (int s = 0; s < 6; ++s) wv[s] = *(const float4*)&wsm[6 * dg + s][ii];
            #pragma unroll
            for (int a_ = 0; a_ < 4; ++a_)
                #pragma unroll
                for (int b_ = 0; b_ < 6; ++b_)
                    acc[a_][b_] += xv[a_].x * wv[b_].x + xv[a_].y * wv[b_].y
                                 + xv[a_].z * wv[b_].z + xv[a_].w * wv[b_].w;
        }
    }

    #pragma unroll
    for (int a_ = 0; a_ < 4; ++a_) {
        int tau = t0 + 4 * tg + a_;
        int b = tau >> 5, q = tau & 31;
        float p = pw[4 * tg + a_];
        #pragma unroll
        for (int b_ = 0; b_ < 6; ++b_) {
            int d = 6 * dg + b_;
            out[((size_t)(b * QS_ + q)) * IN_ + h * HD_ + d] = p * acc[a_][b_];
        }
    }
}

// ---------------- launch ----------------

extern "C" void kernel_launch(void* const* d_in, const int* in_sizes, int n_in,
                              void* d_out, int out_size, void* d_ws, size_t ws_size,
                              hipStream_t stream) {
    const float* origx = (const float*)d_in[0];
    const float* query = (const float*)d_in[1];
    const float* Wq    = (const float*)d_in[2];
    const float* Wk    = (const float*)d_in[3];
    const float* Wv    = (const float*)d_in[4];
    float* out = (float*)d_out;

    // workspace ~1.2 MB
    char* p = (char*)d_ws;
    float* pe32 = (float*)p; p += (size_t)KK_ * IN_ * 4;
    float* qp32 = (float*)p; p += (size_t)QS_ * IN_ * 4;
    float* pool = (float*)p; p += (size_t)B_ * HQ_ * 4;
    int*   idxb = (int*)p;   p += (size_t)B_ * HQ_ * 4;
    (void)ws_size; (void)in_sizes; (void)n_in; (void)out_size;

    dim3 blk(256);
    k_pe<<<dim3((KK_ * IN_ + 255) / 256), blk, 0, stream>>>(pe32);
    k_qproj_np<<<dim3((QS_ * IN_ + 255) / 256), blk, 0, stream>>>(query, Wq, qp32);
    k_score_np<<<dim3(B_ * NH_), blk, 0, stream>>>(origx, pe32, Wk, qp32, pool, idxb);
    k_value<<<dim3(NH_ * 128), blk, 0, stream>>>(origx, pe32, Wv, pool, idxb, out);
}

// Round 11
// 4450.579 us; speedup vs baseline: 17.3286x; 17.3286x over previous
//
#include <hip/hip_runtime.h>
#include <math.h>
#include <float.h>

#define B_   256
#define KK_  196    // 14x14
#define GS_  14
#define IN_  768
#define NH_  8
#define QS_  32
#define HD_  96
#define HQ_  256    // NH_*QS_
#define NT   512    // k_score_np block size

// ---------------- PE: correctly-rounded f32 of the f32-argument chain ----------------
__global__ void k_pe(float* pe32) {
    int e = blockIdx.x * 256 + threadIdx.x;
    if (e >= KK_ * IN_) return;
    int k = e / IN_, i = e - k * IN_;
    int j = i >> 1;
    const float c32 = (float)(-9.210340371976184 / 768.0);  // f32(-ln(1e4)/768)
    float arg = (float)(2 * j) * c32;                        // f32 mul
    float div = (float)exp((double)arg);                     // CR f32 exp
    float ang = (float)k * div;                              // f32 mul
    double vd = (i & 1) ? cos((double)ang) : sin((double)ang);
    pe32[e] = (float)vd;                                     // CR f32 sin/cos
}

// ====== numpy einsum sum_of_products_contig_outstride0_two, SSE3 baseline ======
// Per 16-elem block: ab3=a3*b3+acc; ab2=a2*b2+ab3; ab1=a1*b1+ab2; acc=a0*b0+ab1
// (mul/add UNFUSED). Final reduce: (ac0+ac1)+(ac2+ac3).
__device__ __forceinline__ float np_chain_dot(const float* __restrict__ a,
                                              const float* __restrict__ b, int nblk) {
#pragma clang fp contract(off)
    float ac0 = 0.f, ac1 = 0.f, ac2 = 0.f, ac3 = 0.f;
    for (int blk = 0; blk < nblk; ++blk) {
        const float* xa = a + blk * 16;
        const float* wa = b + blk * 16;
        {
            float t3 = xa[12] * wa[12] + ac0;
            float t2 = xa[8]  * wa[8]  + t3;
            float t1 = xa[4]  * wa[4]  + t2;
            ac0 = xa[0] * wa[0] + t1;
        }
        {
            float t3 = xa[13] * wa[13] + ac1;
            float t2 = xa[9]  * wa[9]  + t3;
            float t1 = xa[5]  * wa[5]  + t2;
            ac1 = xa[1] * wa[1] + t1;
        }
        {
            float t3 = xa[14] * wa[14] + ac2;
            float t2 = xa[10] * wa[10] + t3;
            float t1 = xa[6]  * wa[6]  + t2;
            ac2 = xa[2] * wa[2] + t1;
        }
        {
            float t3 = xa[15] * wa[15] + ac3;
            float t2 = xa[11] * wa[11] + t3;
            float t1 = xa[7]  * wa[7]  + t2;
            ac3 = xa[3] * wa[3] + t1;
        }
    }
    return (ac0 + ac1) + (ac2 + ac3);
}

// qp32[qq][o] = np-bit q = einsum('bqi,oi->bqo', query, W_q)
__global__ void k_qproj_np(const float* __restrict__ query, const float* __restrict__ Wq,
                           float* qp32) {
    int idx = blockIdx.x * 256 + threadIdx.x;
    if (idx >= QS_ * IN_) return;
    int qq = idx / IN_, o = idx - qq * IN_;
    qp32[idx] = np_chain_dot(query + (size_t)qq * IN_, Wq + (size_t)o * IN_, 48);
}

// ====== fused np-f32 score pipeline: k-proj -> attn -> pool -> argmax ======
// block = (b, h), 512 threads. Arithmetic bit-identical to R10 (np f32 bits);
// restructured: static acc slots (no scratch), transposed-W LDS (stride 97,
// conflict-free), 2 k-rows per thread-slot (W reuse).
__global__ __launch_bounds__(NT) void k_score_np(const float* __restrict__ origx,
                                                 const float* __restrict__ pe32,
                                                 const float* __restrict__ Wk,
                                                 const float* __restrict__ qp32,
                                                 float* __restrict__ pool,
                                                 int* __restrict__ idxb) {
#pragma clang fp contract(off)
    int b = blockIdx.x >> 3;     // 256 b x 8 h
    int h = blockIdx.x & 7;
    __shared__ float attn_s[QS_][KK_ + 4];   // 32 x 200 (25.6 KB)
    __shared__ float buf[8576];              // bx | bwT ; reused for ks, pooled (34.3 KB)
    float* bx  = buf;            // [32][64]   x tile
    float* bwT = buf + 2048;     // [64][97]   transposed Wk tile (stride 97 ≡ 1 mod 32)
    int t = threadIdx.x;

    for (int k0 = 0; k0 < KK_; k0 += 32) {
        int rows = (KK_ - k0 < 32) ? (KK_ - k0) : 32;   // 32 or 4 (always even)
        int npair = (rows * HD_) >> 1;                   // dot-pairs this tile
        int oo_[3], rr_[3]; bool ok_[3];
        float acc[3][2][4];
        #pragma unroll
        for (int s = 0; s < 3; ++s) {
            int id = t + NT * s;
            ok_[s] = (id < npair);
            int idc = ok_[s] ? id : 0;
            oo_[s] = idc % HD_;
            rr_[s] = (idc / HD_) * 2;
            #pragma unroll
            for (int u = 0; u < 2; ++u) {
                acc[s][u][0] = 0.f; acc[s][u][1] = 0.f;
                acc[s][u][2] = 0.f; acc[s][u][3] = 0.f;
            }
        }

        for (int i0 = 0; i0 < IN_; i0 += 64) {
            __syncthreads();
            // stage x rows (global coalesced; LDS writes conflict-free)
            for (int e = t; e < rows * 64; e += NT) {
                int rr = e >> 6, cc = e & 63;
                int kk = k0 + rr;
                bx[rr * 64 + cc] = origx[((size_t)b * KK_ + kk) * IN_ + i0 + cc]
                                 + pe32[kk * IN_ + i0 + cc];   // f32 x materialization
            }
            // stage Wk transposed: bwT[cc][oo] (global coalesced; stride 97 -> free)
            for (int e = t; e < HD_ * 64; e += NT) {
                int oo = e >> 6, cc = e & 63;
                bwT[cc * 97 + oo] = Wk[((size_t)(h * HD_ + oo)) * IN_ + i0 + cc];
            }
            __syncthreads();
            #pragma unroll
            for (int s = 0; s < 3; ++s) {
                if (!ok_[s]) continue;
                const float4* x4a = (const float4*)(bx + rr_[s] * 64);        // broadcast
                const float4* x4b = (const float4*)(bx + (rr_[s] + 1) * 64);
                const float* wt = bwT + oo_[s];                                // stride-97 scalar
                #pragma unroll
                for (int blk = 0; blk < 4; ++blk) {
                    float w0x = wt[(blk*16+ 0)*97], w1x = wt[(blk*16+ 4)*97],
                          w2x = wt[(blk*16+ 8)*97], w3x = wt[(blk*16+12)*97];
                    float w0y = wt[(blk*16+ 1)*97], w1y = wt[(blk*16+ 5)*97],
                          w2y = wt[(blk*16+ 9)*97], w3y = wt[(blk*16+13)*97];
                    float w0z = wt[(blk*16+ 2)*97], w1z = wt[(blk*16+ 6)*97],
                          w2z = wt[(blk*16+10)*97], w3z = wt[(blk*16+14)*97];
                    float w0w = wt[(blk*16+ 3)*97], w1w = wt[(blk*16+ 7)*97],
                          w2w = wt[(blk*16+11)*97], w3w = wt[(blk*16+15)*97];
                    float4 xa0 = x4a[blk*4+0], xa1 = x4a[blk*4+1];
                    float4 xa2 = x4a[blk*4+2], xa3 = x4a[blk*4+3];
                    float t3, t2, t1;
                    t3 = xa3.x*w3x + acc[s][0][0]; t2 = xa2.x*w2x + t3;
                    t1 = xa1.x*w1x + t2;           acc[s][0][0] = xa0.x*w0x + t1;
                    t3 = xa3.y*w3y + acc[s][0][1]; t2 = xa2.y*w2y + t3;
                    t1 = xa1.y*w1y + t2;           acc[s][0][1] = xa0.y*w0y + t1;
                    t3 = xa3.z*w3z + acc[s][0][2]; t2 = xa2.z*w2z + t3;
                    t1 = xa1.z*w1z + t2;           acc[s][0][2] = xa0.z*w0z + t1;
                    t3 = xa3.w*w3w + acc[s][0][3]; t2 = xa2.w*w2w + t3;
                    t1 = xa1.w*w1w + t2;           acc[s][0][3] = xa0.w*w0w + t1;
                    float4 xb0 = x4b[blk*4+0], xb1 = x4b[blk*4+1];
                    float4 xb2 = x4b[blk*4+2], xb3 = x4b[blk*4+3];
                    t3 = xb3.x*w3x + acc[s][1][0]; t2 = xb2.x*w2x + t3;
                    t1 = xb1.x*w1x + t2;           acc[s][1][0] = xb0.x*w0x + t1;
                    t3 = xb3.y*w3y + acc[s][1][1]; t2 = xb2.y*w2y + t3;
                    t1 = xb1.y*w1y + t2;           acc[s][1][1] = xb0.y*w0y + t1;
                    t3 = xb3.z*w3z + acc[s][1][2]; t2 = xb2.z*w2z + t3;
                    t1 = xb1.z*w1z + t2;           acc[s][1][2] = xb0.z*w0z + t1;
                    t3 = xb3.w*w3w + acc[s][1][3]; t2 = xb2.w*w2w + t3;
                    t1 = xb1.w*w1w + t2;           acc[s][1][3] = xb0.w*w0w + t1;
                }
            }
        }
        __syncthreads();
        // ks[kk][oo] = np hadd reduce (reuse buf, stride 100)
        #pragma unroll
        for (int s = 0; s < 3; ++s) {
            if (!ok_[s]) continue;
            buf[rr_[s] * 100 + oo_[s]] =
                (acc[s][0][0] + acc[s][0][1]) + (acc[s][0][2] + acc[s][0][3]);
            buf[(rr_[s] + 1) * 100 + oo_[s]] =
                (acc[s][1][0] + acc[s][1][1]) + (acc[s][1][2] + acc[s][1][3]);
        }
        __syncthreads();
        // attn = einsum('hqd,bhkd->bhqk') np bits: 96-chain (6 blocks)
        int adots = QS_ * rows;
        for (int e = t; e < adots; e += NT) {
            int q = e / rows, kk = e - q * rows;
            attn_s[q][k0 + kk] = np_chain_dot(qp32 + (size_t)q * IN_ + h * HD_,
                                              buf + kk * 100, 6);
        }
        __syncthreads();
    }

    // 3x3 avgpool: sequential row-major in-bounds adds, /9.0f (np bits)
    for (int e = t; e < QS_ * KK_; e += NT) {
        int q = e / KK_, kk = e - q * KK_;
        int r = kk / GS_, c = kk - r * GS_;
        float s = 0.f;
        for (int di = -1; di <= 1; ++di) {
            int rr = r + di; if (rr < 0 || rr >= GS_) continue;
            for (int dj = -1; dj <= 1; ++dj) {
                int cc = c + dj; if (cc < 0 || cc >= GS_) continue;
                s += attn_s[q][rr * GS_ + cc];
            }
        }
        buf[q * 200 + kk] = s / 9.0f;
    }
    __syncthreads();
    // first-max argmax per q row (np.argmax semantics)
    if (t < QS_) {
        const float* pr = buf + t * 200;
        float m = pr[0]; int im = 0;
        for (int kk = 1; kk < KK_; ++kk) {
            float v = pr[kk];
            if (v > m) { m = v; im = kk; }
        }
        int row = b * HQ_ + h * QS_ + t;
        pool[row] = m;
        idxb[row] = im;
    }
}

// ---------------- value gather GEMM (f32; bf16-level tolerance) ----------------
__global__ __launch_bounds__(256) void k_value(const float* __restrict__ origx,
                                               const float* __restrict__ pe32,
                                               const float* __restrict__ Wv,
                                               const float* __restrict__ pool,
                                               const int* __restrict__ idxb,
                                               float* __restrict__ out) {
    int h = blockIdx.x >> 7;
    int blk = blockIdx.x & 127;
    int t0 = blk * 64;
    __shared__ float xs[64][68];
    __shared__ float wsm[HD_][68];
    __shared__ int   kidx[64];
    __shared__ float pw[64];
    int t = threadIdx.x;
    if (t < 64) {
        int tau = t0 + t;
        int b = tau >> 5, q = tau & 31;
        int row = b * HQ_ + h * QS_ + q;
        kidx[t] = idxb[row];
        pw[t] = pool[row];
    }
    __syncthreads();

    int tg = t & 15;
    int dg = t >> 4;
    float acc[4][6] = {};

    for (int i0 = 0; i0 < IN_; i0 += 64) {
        __syncthreads();
        for (int e = t; e < 64 * 64; e += 256) {
            int rr = e >> 6, cc = e & 63;
            int tau = t0 + rr;
            int b = tau >> 5;
            int kk = kidx[rr];
            xs[rr][cc] = origx[((size_t)b * KK_ + kk) * IN_ + i0 + cc]
                       + pe32[kk * IN_ + i0 + cc];
        }
        for (int e = t; e < HD_ * 64; e += 256) {
            int rr = e >> 6, cc = e & 63;
            wsm[rr][cc] = Wv[((size_t)(h * HD_ + rr)) * IN_ + i0 + cc];
        }
        __syncthreads();
        for (int ii = 0; ii < 64; ii += 4) {
            float4 xv[4], wv[6];
            #pragma unroll
            for (int s = 0; s < 4; ++s) xv[s] = *(const float4*)&xs[4 * tg + s][ii];
            #pragma unroll
            for (int s = 0; s < 6; ++s) wv[s] = *(const float4*)&wsm[6 * dg + s][ii];
            #pragma unroll
            for (int a_ = 0; a_ < 4; ++a_)
                #pragma unroll
                for (int b_ = 0; b_ < 6; ++b_)
                    acc[a_][b_] += xv[a_].x * wv[b_].x + xv[a_].y * wv[b_].y
                                 + xv[a_].z * wv[b_].z + xv[a_].w * wv[b_].w;
        }
    }

    #pragma unroll
    for (int a_ = 0; a_ < 4; ++a_) {
        int tau = t0 + 4 * tg + a_;
        int b = tau >> 5, q = tau & 31;
        float p = pw[4 * tg + a_];
        #pragma unroll
        for (int b_ = 0; b_ < 6; ++b_) {
            int d = 6 * dg + b_;
            out[((size_t)(b * QS_ + q)) * IN_ + h * HD_ + d] = p * acc[a_][b_];
        }
    }
}

// ---------------- launch ----------------

extern "C" void kernel_launch(void* const* d_in, const int* in_sizes, int n_in,
                              void* d_out, int out_size, void* d_ws, size_t ws_size,
                              hipStream_t stream) {
    const float* origx = (const float*)d_in[0];
    const float* query = (const float*)d_in[1];
    const float* Wq    = (const float*)d_in[2];
    const float* Wk    = (const float*)d_in[3];
    const float* Wv    = (const float*)d_in[4];
    float* out = (float*)d_out;

    // workspace ~1.2 MB
    char* p = (char*)d_ws;
    float* pe32 = (float*)p; p += (size_t)KK_ * IN_ * 4;
    float* qp32 = (float*)p; p += (size_t)QS_ * IN_ * 4;
    float* pool = (float*)p; p += (size_t)B_ * HQ_ * 4;
    int*   idxb = (int*)p;   p += (size_t)B_ * HQ_ * 4;
    (void)ws_size; (void)in_sizes; (void)n_in; (void)out_size;

    k_pe<<<dim3((KK_ * IN_ + 255) / 256), dim3(256), 0, stream>>>(pe32);
    k_qproj_np<<<dim3((QS_ * IN_ + 255) / 256), dim3(256), 0, stream>>>(query, Wq, qp32);
    k_score_np<<<dim3(B_ * NH_), dim3(NT), 0, stream>>>(origx, pe32, Wk, qp32, pool, idxb);
    k_value<<<dim3(NH_ * 128), dim3(256), 0, stream>>>(origx, pe32, Wv, pool, idxb, out);
}

// Round 12
// 4354.832 us; speedup vs baseline: 17.7096x; 1.0220x over previous
//
#include <hip/hip_runtime.h>
#include <math.h>
#include <float.h>

#define B_   256
#define KK_  196    // 14x14
#define GS_  14
#define IN_  768
#define NH_  8
#define QS_  32
#define HD_  96
#define HQ_  256    // NH_*QS_
#define NT   384    // k_score_np block size

// ---------------- PE: correctly-rounded f32 of the f32-argument chain ----------------
__global__ void k_pe(float* pe32) {
    int e = blockIdx.x * 256 + threadIdx.x;
    if (e >= KK_ * IN_) return;
    int k = e / IN_, i = e - k * IN_;
    int j = i >> 1;
    const float c32 = (float)(-9.210340371976184 / 768.0);  // f32(-ln(1e4)/768)
    float arg = (float)(2 * j) * c32;                        // f32 mul
    float div = (float)exp((double)arg);                     // CR f32 exp
    float ang = (float)k * div;                              // f32 mul
    double vd = (i & 1) ? cos((double)ang) : sin((double)ang);
    pe32[e] = (float)vd;                                     // CR f32 sin/cos
}

// ====== numpy einsum sum_of_products_contig_outstride0_two, SSE3 baseline ======
// Per 16-elem block: ab3=a3*b3+acc; ab2=a2*b2+ab3; ab1=a1*b1+ab2; acc=a0*b0+ab1
// (mul/add UNFUSED). Final reduce: (ac0+ac1)+(ac2+ac3).
__device__ __forceinline__ float np_chain_dot(const float* __restrict__ a,
                                              const float* __restrict__ b, int nblk) {
#pragma clang fp contract(off)
    float ac0 = 0.f, ac1 = 0.f, ac2 = 0.f, ac3 = 0.f;
    for (int blk = 0; blk < nblk; ++blk) {
        const float* xa = a + blk * 16;
        const float* wa = b + blk * 16;
        {
            float t3 = xa[12] * wa[12] + ac0;
            float t2 = xa[8]  * wa[8]  + t3;
            float t1 = xa[4]  * wa[4]  + t2;
            ac0 = xa[0] * wa[0] + t1;
        }
        {
            float t3 = xa[13] * wa[13] + ac1;
            float t2 = xa[9]  * wa[9]  + t3;
            float t1 = xa[5]  * wa[5]  + t2;
            ac1 = xa[1] * wa[1] + t1;
        }
        {
            float t3 = xa[14] * wa[14] + ac2;
            float t2 = xa[10] * wa[10] + t3;
            float t1 = xa[6]  * wa[6]  + t2;
            ac2 = xa[2] * wa[2] + t1;
        }
        {
            float t3 = xa[15] * wa[15] + ac3;
            float t2 = xa[11] * wa[11] + t3;
            float t1 = xa[7]  * wa[7]  + t2;
            ac3 = xa[3] * wa[3] + t1;
        }
    }
    return (ac0 + ac1) + (ac2 + ac3);
}

// qp32[qq][o] = np-bit q = einsum('bqi,oi->bqo', query, W_q)
__global__ void k_qproj_np(const float* __restrict__ query, const float* __restrict__ Wq,
                           float* qp32) {
    int idx = blockIdx.x * 256 + threadIdx.x;
    if (idx >= QS_ * IN_) return;
    int qq = idx / IN_, o = idx - qq * IN_;
    qp32[idx] = np_chain_dot(query + (size_t)qq * IN_, Wq + (size_t)o * IN_, 48);
}

// ====== fused np-f32 score pipeline: k-proj -> attn -> pool -> argmax ======
// block = (b, h), 384 threads. Bits identical to R11; 4x4 register tiling so
// VALU (not LDS issue) is the limiter. W rows spaced 24 -> conflict-free b128.
__global__ __launch_bounds__(NT) void k_score_np(const float* __restrict__ origx,
                                                 const float* __restrict__ pe32,
                                                 const float* __restrict__ Wk,
                                                 const float* __restrict__ qp32,
                                                 float* __restrict__ pool,
                                                 int* __restrict__ idxb) {
#pragma clang fp contract(off)
    int b = blockIdx.x >> 3;     // 256 b x 8 h
    int h = blockIdx.x & 7;
    __shared__ float attn_s[QS_][KK_ + 4];        // 25.6 KB
    __shared__ __align__(16) float buf[6144];     // bx[64][36] | bw[96][36] ; reused: ks[64][96]; partials
    __shared__ float qph[QS_ * 97];               // 12.4 KB, stride 97 -> conflict-free
    float* bx = buf;             // [64][36]
    float* bw = buf + 2304;      // [96][36]
    float* ks = buf;             // [64][96] (overlays bx|bw after compute)
    int t = threadIdx.x;

    // stage q-projection slice for this head
    for (int e = t; e < QS_ * HD_; e += NT) {
        int q = e / HD_, pos = e - q * HD_;
        qph[q * 97 + pos] = qp32[(size_t)q * IN_ + h * HD_ + pos];
    }

    int cg = t % 24;             // col group: oo = cg + 24*cj
    int rg = t / 24;             // row group: r  = rg + 16*rj  (0..15)

    for (int k0 = 0; k0 < KK_; k0 += 64) {
        int rows = (KK_ - k0 < 64) ? (KK_ - k0) : 64;
        if (rows == 64) {
            float acc[4][4][4];
            #pragma unroll
            for (int rj = 0; rj < 4; ++rj)
                #pragma unroll
                for (int cj = 0; cj < 4; ++cj) {
                    acc[rj][cj][0] = 0.f; acc[rj][cj][1] = 0.f;
                    acc[rj][cj][2] = 0.f; acc[rj][cj][3] = 0.f;
                }
            for (int i0 = 0; i0 < IN_; i0 += 32) {
                __syncthreads();   // also protects ks of previous tile
                for (int e = t; e < 64 * 32; e += NT) {
                    int rr = e >> 5, cc = e & 31;
                    int kk = k0 + rr;
                    bx[rr * 36 + cc] = origx[((size_t)b * KK_ + kk) * IN_ + i0 + cc]
                                     + pe32[kk * IN_ + i0 + cc];   // f32 x materialization
                }
                for (int e = t; e < 96 * 32; e += NT) {
                    int oo = e >> 5, cc = e & 31;
                    bw[oo * 36 + cc] = Wk[((size_t)(h * HD_ + oo)) * IN_ + i0 + cc];
                }
                __syncthreads();
                #pragma unroll
                for (int blk2 = 0; blk2 < 2; ++blk2) {
                    float4 xf[4][4];
                    #pragma unroll
                    for (int rj = 0; rj < 4; ++rj) {
                        const float4* xr = (const float4*)(bx + (rg + 16 * rj) * 36 + blk2 * 16);
                        xf[rj][0] = xr[0]; xf[rj][1] = xr[1];
                        xf[rj][2] = xr[2]; xf[rj][3] = xr[3];
                    }
                    #pragma unroll
                    for (int cj = 0; cj < 4; ++cj) {
                        const float4* wr = (const float4*)(bw + (cg + 24 * cj) * 36 + blk2 * 16);
                        float4 w0 = wr[0], w1 = wr[1], w2 = wr[2], w3 = wr[3];
                        #pragma unroll
                        for (int rj = 0; rj < 4; ++rj) {
                            float t3, t2, t1;
                            t3 = xf[rj][3].x * w3.x + acc[rj][cj][0];
                            t2 = xf[rj][2].x * w2.x + t3;
                            t1 = xf[rj][1].x * w1.x + t2;
                            acc[rj][cj][0] = xf[rj][0].x * w0.x + t1;
                            t3 = xf[rj][3].y * w3.y + acc[rj][cj][1];
                            t2 = xf[rj][2].y * w2.y + t3;
                            t1 = xf[rj][1].y * w1.y + t2;
                            acc[rj][cj][1] = xf[rj][0].y * w0.y + t1;
                            t3 = xf[rj][3].z * w3.z + acc[rj][cj][2];
                            t2 = xf[rj][2].z * w2.z + t3;
                            t1 = xf[rj][1].z * w1.z + t2;
                            acc[rj][cj][2] = xf[rj][0].z * w0.z + t1;
                            t3 = xf[rj][3].w * w3.w + acc[rj][cj][3];
                            t2 = xf[rj][2].w * w2.w + t3;
                            t1 = xf[rj][1].w * w1.w + t2;
                            acc[rj][cj][3] = xf[rj][0].w * w0.w + t1;
                        }
                    }
                }
            }
            __syncthreads();   // all reads of bx/bw done before ks overwrite
            #pragma unroll
            for (int rj = 0; rj < 4; ++rj)
                #pragma unroll
                for (int cj = 0; cj < 4; ++cj)
                    ks[(rg + 16 * rj) * 96 + cg + 24 * cj] =
                        (acc[rj][cj][0] + acc[rj][cj][1]) + (acc[rj][cj][2] + acc[rj][cj][3]);
        } else {
            // tail tile (rows = 4): one dot per thread
            int rr = t / 96, oo = t - (t / 96) * 96;
            float ac[4] = {0.f, 0.f, 0.f, 0.f};
            for (int i0 = 0; i0 < IN_; i0 += 32) {
                __syncthreads();
                for (int e = t; e < rows * 32; e += NT) {
                    int r2 = e >> 5, cc = e & 31;
                    int kk = k0 + r2;
                    bx[r2 * 36 + cc] = origx[((size_t)b * KK_ + kk) * IN_ + i0 + cc]
                                     + pe32[kk * IN_ + i0 + cc];
                }
                for (int e = t; e < 96 * 32; e += NT) {
                    int oo2 = e >> 5, cc = e & 31;
                    bw[oo2 * 36 + cc] = Wk[((size_t)(h * HD_ + oo2)) * IN_ + i0 + cc];
                }
                __syncthreads();
                #pragma unroll
                for (int blk2 = 0; blk2 < 2; ++blk2) {
                    const float* xa = bx + rr * 36 + blk2 * 16;
                    const float* wa = bw + oo * 36 + blk2 * 16;
                    float t3, t2, t1;
                    t3 = xa[12] * wa[12] + ac[0]; t2 = xa[8]  * wa[8]  + t3;
                    t1 = xa[4]  * wa[4]  + t2;    ac[0] = xa[0] * wa[0] + t1;
                    t3 = xa[13] * wa[13] + ac[1]; t2 = xa[9]  * wa[9]  + t3;
                    t1 = xa[5]  * wa[5]  + t2;    ac[1] = xa[1] * wa[1] + t1;
                    t3 = xa[14] * wa[14] + ac[2]; t2 = xa[10] * wa[10] + t3;
                    t1 = xa[6]  * wa[6]  + t2;    ac[2] = xa[2] * wa[2] + t1;
                    t3 = xa[15] * wa[15] + ac[3]; t2 = xa[11] * wa[11] + t3;
                    t1 = xa[7]  * wa[7]  + t2;    ac[3] = xa[3] * wa[3] + t1;
                }
            }
            __syncthreads();
            ks[rr * 96 + oo] = (ac[0] + ac[1]) + (ac[2] + ac[3]);
        }
        __syncthreads();
        // attn = einsum('hqd,bhkd->bhqk') np bits: lanes share ks row (broadcast)
        for (int e = t; e < QS_ * rows; e += NT) {
            int q = e & 31, kk = e >> 5;
            attn_s[q][k0 + kk] = np_chain_dot(qph + q * 97, ks + kk * 96, 6);
        }
        // loop-top sync protects ks before next staging
    }
    __syncthreads();

    // 3x3 avgpool (row-major in-bounds adds, /9.0f) + chunked first-max argmax
    float* part_m = buf;
    int*   part_i = (int*)(buf + NT);
    {
        int q = t / 12, c = t % 12;
        int kklo = c * 17, kkhi = kklo + 17; if (kkhi > KK_) kkhi = KK_;
        float m = -FLT_MAX; int im = kklo;
        for (int kk = kklo; kk < kkhi; ++kk) {
            int r = kk / GS_, c0 = kk - r * GS_;
            float s = 0.f;
            for (int di = -1; di <= 1; ++di) {
                int rr2 = r + di; if (rr2 < 0 || rr2 >= GS_) continue;
                for (int dj = -1; dj <= 1; ++dj) {
                    int cc2 = c0 + dj; if (cc2 < 0 || cc2 >= GS_) continue;
                    s += attn_s[q][rr2 * GS_ + cc2];
                }
            }
            s = s / 9.0f;
            if (s > m) { m = s; im = kk; }   // strict >: first-max wins
        }
        part_m[t] = m; part_i[t] = im;
    }
    __syncthreads();
    if (t < QS_) {
        float m = -FLT_MAX; int im = 0;
        for (int c = 0; c < 12; ++c) {       // ascending kk chunks; strict >
            float v = part_m[t * 12 + c];
            if (v > m) { m = v; im = part_i[t * 12 + c]; }
        }
        int row = b * HQ_ + h * QS_ + t;
        pool[row] = m;
        idxb[row] = im;
    }
}

// ---------------- value gather GEMM (f32; bf16-level tolerance) ----------------
__global__ __launch_bounds__(256) void k_value(const float* __restrict__ origx,
                                               const float* __restrict__ pe32,
                                               const float* __restrict__ Wv,
                                               const float* __restrict__ pool,
                                               const int* __restrict__ idxb,
                                               float* __restrict__ out) {
    int h = blockIdx.x >> 7;
    int blk = blockIdx.x & 127;
    int t0 = blk * 64;
    __shared__ float xs[64][68];
    __shared__ float wsm[HD_][68];
    __shared__ int   kidx[64];
    __shared__ float pw[64];
    int t = threadIdx.x;
    if (t < 64) {
        int tau = t0 + t;
        int b = tau >> 5, q = tau & 31;
        int row = b * HQ_ + h * QS_ + q;
        kidx[t] = idxb[row];
        pw[t] = pool[row];
    }
    __syncthreads();

    int tg = t & 15;
    int dg = t >> 4;
    float acc[4][6] = {};

    for (int i0 = 0; i0 < IN_; i0 += 64) {
        __syncthreads();
        for (int e = t; e < 64 * 64; e += 256) {
            int rr = e >> 6, cc = e & 63;
            int tau = t0 + rr;
            int b = tau >> 5;
            int kk = kidx[rr];
            xs[rr][cc] = origx[((size_t)b * KK_ + kk) * IN_ + i0 + cc]
                       + pe32[kk * IN_ + i0 + cc];
        }
        for (int e = t; e < HD_ * 64; e += 256) {
            int rr = e >> 6, cc = e & 63;
            wsm[rr][cc] = Wv[((size_t)(h * HD_ + rr)) * IN_ + i0 + cc];
        }
        __syncthreads();
        for (int ii = 0; ii < 64; ii += 4) {
            float4 xv[4], wv[6];
            #pragma unroll
            for (int s = 0; s < 4; ++s) xv[s] = *(const float4*)&xs[4 * tg + s][ii];
            #pragma unroll
            for (int s = 0; s < 6; ++s) wv[s] = *(const float4*)&wsm[6 * dg + s][ii];
            #pragma unroll
            for (int a_ = 0; a_ < 4; ++a_)
                #pragma unroll
                for (int b_ = 0; b_ < 6; ++b_)
                    acc[a_][b_] += xv[a_].x * wv[b_].x + xv[a_].y * wv[b_].y
                                 + xv[a_].z * wv[b_].z + xv[a_].w * wv[b_].w;
        }
    }

    #pragma unroll
    for (int a_ = 0; a_ < 4; ++a_) {
        int tau = t0 + 4 * tg + a_;
        int b = tau >> 5, q = tau & 31;
        float p = pw[4 * tg + a_];
        #pragma unroll
        for (int b_ = 0; b_ < 6; ++b_) {
            int d = 6 * dg + b_;
            out[((size_t)(b * QS_ + q)) * IN_ + h * HD_ + d] = p * acc[a_][b_];
        }
    }
}

// ---------------- launch ----------------

extern "C" void kernel_launch(void* const* d_in, const int* in_sizes, int n_in,
                              void* d_out, int out_size, void* d_ws, size_t ws_size,
                              hipStream_t stream) {
    const float* origx = (const float*)d_in[0];
    const float* query = (const float*)d_in[1];
    const float* Wq    = (const float*)d_in[2];
    const float* Wk    = (const float*)d_in[3];
    const float* Wv    = (const float*)d_in[4];
    float* out = (float*)d_out;

    // workspace ~1.2 MB
    char* p = (char*)d_ws;
    float* pe32 = (float*)p; p += (size_t)KK_ * IN_ * 4;
    float* qp32 = (float*)p; p += (size_t)QS_ * IN_ * 4;
    float* pool = (float*)p; p += (size_t)B_ * HQ_ * 4;
    int*   idxb = (int*)p;   p += (size_t)B_ * HQ_ * 4;
    (void)ws_size; (void)in_sizes; (void)n_in; (void)out_size;

    k_pe<<<dim3((KK_ * IN_ + 255) / 256), dim3(256), 0, stream>>>(pe32);
    k_qproj_np<<<dim3((QS_ * IN_ + 255) / 256), dim3(256), 0, stream>>>(query, Wq, qp32);
    k_score_np<<<dim3(B_ * NH_), dim3(NT), 0, stream>>>(origx, pe32, Wk, qp32, pool, idxb);
    k_value<<<dim3(NH_ * 128), dim3(256), 0, stream>>>(origx, pe32, Wv, pool, idxb, out);
}